// Round 4
// baseline (312.659 us; speedup 1.0000x reference)
//
#include <hip/hip_runtime.h>
#include <hip/hip_bf16.h>
#include <stdint.h>
#include <math.h>

typedef __attribute__((ext_vector_type(8))) short short8;
typedef __attribute__((ext_vector_type(4))) float f32x4;

#define H_DIM 1024
#define T_SEQ 4096
#define BM 128
#define BN 128
#define BK 32

static __device__ __forceinline__ float bf2f(unsigned short u) {
  union { unsigned int i; float f; } c;
  c.i = ((unsigned int)u) << 16;
  return c.f;
}

static __device__ __forceinline__ unsigned short f2bf(float f) {
  __hip_bfloat16 h = __float2bfloat16(f);  // RNE
  unsigned short u;
  __builtin_memcpy(&u, &h, 2);
  return u;
}

static __device__ __forceinline__ void gload16(const void* g, void* l) {
  __builtin_amdgcn_global_load_lds(
      (const __attribute__((address_space(1))) void*)g,
      (__attribute__((address_space(3))) void*)l,
      16, 0, 0);
}

// ---------------------------------------------------------------------------
// f32 -> bf16 conversion, 8 elements/thread/iter (float4 x2 in, short8 out).
// ---------------------------------------------------------------------------
__global__ __launch_bounds__(256) void cvt_kernel(
    const float* __restrict__ in, __hip_bfloat16* __restrict__ out, int n8)
{
  int i = blockIdx.x * blockDim.x + threadIdx.x;
  const int stride = gridDim.x * blockDim.x;
  for (; i < n8; i += stride) {
    const float4* p = (const float4*)in + (size_t)i * 2;
    float4 a = p[0], b = p[1];
    short8 o;
    o[0] = (short)f2bf(a.x); o[1] = (short)f2bf(a.y);
    o[2] = (short)f2bf(a.z); o[3] = (short)f2bf(a.w);
    o[4] = (short)f2bf(b.x); o[5] = (short)f2bf(b.y);
    o[6] = (short)f2bf(b.z); o[7] = (short)f2bf(b.w);
    ((short8*)out)[i] = o;
  }
}

// Same, for the three weight matrices in one launch (blockIdx.y selects).
__global__ __launch_bounds__(256) void cvt3_kernel(
    const float* __restrict__ i0, const float* __restrict__ i1,
    const float* __restrict__ i2,
    __hip_bfloat16* __restrict__ o0, __hip_bfloat16* __restrict__ o1,
    __hip_bfloat16* __restrict__ o2, int n8)
{
  const float* in = (blockIdx.y == 0) ? i0 : ((blockIdx.y == 1) ? i1 : i2);
  __hip_bfloat16* out = (blockIdx.y == 0) ? o0 : ((blockIdx.y == 1) ? o1 : o2);
  int i = blockIdx.x * blockDim.x + threadIdx.x;
  const int stride = gridDim.x * blockDim.x;
  for (; i < n8; i += stride) {
    const float4* p = (const float4*)in + (size_t)i * 2;
    float4 a = p[0], b = p[1];
    short8 o;
    o[0] = (short)f2bf(a.x); o[1] = (short)f2bf(a.y);
    o[2] = (short)f2bf(a.z); o[3] = (short)f2bf(a.w);
    o[4] = (short)f2bf(b.x); o[5] = (short)f2bf(b.y);
    o[6] = (short)f2bf(b.z); o[7] = (short)f2bf(b.w);
    ((short8*)out)[i] = o;
  }
}

// ---------------------------------------------------------------------------
// Fused QKV projection: out = X @ W^T + b for W in {Wq, Wk, Wv} (bf16 copies).
// m97 structure: 128x128 tile, BK=32, 4 waves (2x2), 16x16x32 bf16 MFMA,
// global_load_lds width-16 staging, 2 barriers per K-step. Bias is f32.
// ---------------------------------------------------------------------------
__global__ __launch_bounds__(256) void qkv_gemm_kernel(
    const __hip_bfloat16* __restrict__ X,
    const __hip_bfloat16* __restrict__ Wq,
    const __hip_bfloat16* __restrict__ Wk,
    const __hip_bfloat16* __restrict__ Wv,
    const float* __restrict__ bq,
    const float* __restrict__ bk,
    const float* __restrict__ bv,
    __hip_bfloat16* __restrict__ Qo,
    __hip_bfloat16* __restrict__ Ko,
    __hip_bfloat16* __restrict__ Vo,
    int M)
{
  __shared__ __hip_bfloat16 sA[BM * BK];   // 8 KiB
  __shared__ __hip_bfloat16 sB[BN * BK];   // 8 KiB

  const int m0 = blockIdx.x * BM;
  const int ytile = blockIdx.y;           // 0..23
  const int which = ytile >> 3;           // 0:Q 1:K 2:V
  const int n_local = (ytile & 7) * BN;   // 0..896 within the selected W

  const __hip_bfloat16* Wsel = (which == 0) ? Wq : ((which == 1) ? Wk : Wv);
  const float* Bsel          = (which == 0) ? bq : ((which == 1) ? bk : bv);
  __hip_bfloat16* Osel       = (which == 0) ? Qo : ((which == 1) ? Ko : Vo);

  const int tid  = threadIdx.x;
  const int lane = tid & 63;
  const int wv   = tid >> 6;        // wave 0..3
  const int wm   = (wv >> 1) * 64;  // wave tile row origin
  const int wn   = (wv & 1) * 64;   // wave tile col origin

  f32x4 acc[4][4];
  #pragma unroll
  for (int i = 0; i < 4; ++i)
    #pragma unroll
    for (int j = 0; j < 4; ++j)
      acc[i][j] = (f32x4){0.f, 0.f, 0.f, 0.f};

  const int ar = wm + (lane & 15);  // A fragment row within tile
  const int br = wn + (lane & 15);  // B fragment row (= output col) within tile
  const int kq = lane >> 4;         // k-quarter 0..3 (8 bf16 each)

  const int nkt = H_DIM / BK;       // 32 K-steps

  for (int kt = 0; kt < nkt; ++kt) {
    const int k0 = kt * BK;
    // Stage A/B tiles: each 128x32 bf16 = 8 KiB = 512 chunks of 16 B.
    // LDS layout linear [row][32] (required by global_load_lds wave-uniform
    // dest: per-wave pointers are base + lane*16 by construction).
    #pragma unroll
    for (int i = 0; i < 2; ++i) {
      int idx = i * 256 + tid;
      int row = idx >> 2;
      int ck  = (idx & 3) * 8;
      gload16(X    + (size_t)(m0 + row)      * H_DIM + k0 + ck, (char*)sA + idx * 16);
      gload16(Wsel + (size_t)(n_local + row) * H_DIM + k0 + ck, (char*)sB + idx * 16);
    }
    __syncthreads();

    const short8* pA = (const short8*)sA;
    const short8* pB = (const short8*)sB;
    short8 afrag[4], bfrag[4];
    #pragma unroll
    for (int mi = 0; mi < 4; ++mi)
      afrag[mi] = pA[(ar + mi * 16) * 4 + kq];
    #pragma unroll
    for (int ni = 0; ni < 4; ++ni)
      bfrag[ni] = pB[(br + ni * 16) * 4 + kq];

    #pragma unroll
    for (int mi = 0; mi < 4; ++mi)
      #pragma unroll
      for (int ni = 0; ni < 4; ++ni)
        acc[mi][ni] = __builtin_amdgcn_mfma_f32_16x16x32_bf16(
            afrag[mi], bfrag[ni], acc[mi][ni], 0, 0, 0);

    __syncthreads();
  }

  // Epilogue: f32 bias add + bf16 store.
  // C/D layout (verified m89/m91): col = lane&15, row = (lane>>4)*4 + reg.
  #pragma unroll
  for (int ni = 0; ni < 4; ++ni) {
    const int col = n_local + wn + ni * 16 + (lane & 15);
    const float bias = Bsel[col];
    #pragma unroll
    for (int mi = 0; mi < 4; ++mi) {
      const int rowbase = m0 + wm + mi * 16 + (lane >> 4) * 4;
      #pragma unroll
      for (int r = 0; r < 4; ++r) {
        float v = acc[mi][ni][r] + bias;
        Osel[(size_t)(rowbase + r) * H_DIM + col] = __float2bfloat16(v);
      }
    }
  }
}

// ---------------------------------------------------------------------------
// Windowed causal attention. One wave per (b,t) row.
// Q/K/V are bf16 (from GEMM); output is f32.
// Each lane owns 16 of the 1024 head dims. Scores via per-lane FMA + wave
// butterfly reduce; f32 softmax in registers; weighted V sum; f32 store.
// ---------------------------------------------------------------------------
__global__ __launch_bounds__(256) void local_attn_kernel(
    const __hip_bfloat16* __restrict__ Q,
    const __hip_bfloat16* __restrict__ Km,
    const __hip_bfloat16* __restrict__ V,
    const int* __restrict__ winp,
    float* __restrict__ Out,
    int M)
{
  const int row = (int)((blockIdx.x * blockDim.x + threadIdx.x) >> 6);
  if (row >= M) return;
  const int lane = threadIdx.x & 63;
  const int t = row & (T_SEQ - 1);
  const int Wn = *winp;  // 8 for this problem
  const float scale = 0.03125f;  // 1/sqrt(1024)

  const size_t base = (size_t)row * H_DIM + (size_t)lane * 16;

  float q[16];
  {
    const short8* p = (const short8*)(Q + base);
    short8 a = p[0], b = p[1];
    #pragma unroll
    for (int j = 0; j < 8; ++j) {
      q[j]     = bf2f((unsigned short)a[j]);
      q[8 + j] = bf2f((unsigned short)b[j]);
    }
  }

  if (Wn == 8) {
    // Fast path: fully unrolled, static indexing (keeps sc[] in registers).
    float sc[9];
    #pragma unroll
    for (int w = 0; w < 9; ++w) {
      const int dt = 8 - w;
      float s = -INFINITY;
      if (t - dt >= 0) {
        const short8* kp = (const short8*)(Km + base - (size_t)dt * H_DIM);
        short8 ka = kp[0], kb = kp[1];
        float d = 0.f;
        #pragma unroll
        for (int j = 0; j < 8; ++j) {
          d += q[j]     * bf2f((unsigned short)ka[j]);
          d += q[8 + j] * bf2f((unsigned short)kb[j]);
        }
        #pragma unroll
        for (int off = 32; off >= 1; off >>= 1) d += __shfl_xor(d, off, 64);
        s = d * scale;
      }
      sc[w] = s;
    }
    float m = sc[0];
    #pragma unroll
    for (int w = 1; w < 9; ++w) m = fmaxf(m, sc[w]);
    float l = 0.f;
    #pragma unroll
    for (int w = 0; w < 9; ++w) { sc[w] = __expf(sc[w] - m); l += sc[w]; }
    const float inv = 1.f / l;

    float o[16];
    #pragma unroll
    for (int j = 0; j < 16; ++j) o[j] = 0.f;
    #pragma unroll
    for (int w = 0; w < 9; ++w) {
      const int dt = 8 - w;
      if (t - dt >= 0) {
        const short8* vp = (const short8*)(V + base - (size_t)dt * H_DIM);
        short8 va = vp[0], vb = vp[1];
        const float aw = sc[w] * inv;
        #pragma unroll
        for (int j = 0; j < 8; ++j) {
          o[j]     += aw * bf2f((unsigned short)va[j]);
          o[8 + j] += aw * bf2f((unsigned short)vb[j]);
        }
      }
    }

    float4* op = (float4*)(Out + base);
    op[0] = (float4){o[0],  o[1],  o[2],  o[3]};
    op[1] = (float4){o[4],  o[5],  o[6],  o[7]};
    op[2] = (float4){o[8],  o[9],  o[10], o[11]};
    op[3] = (float4){o[12], o[13], o[14], o[15]};
  } else {
    // Generic fallback: online softmax, no runtime-indexed arrays.
    float m = -INFINITY, l = 0.f;
    float o[16];
    #pragma unroll
    for (int j = 0; j < 16; ++j) o[j] = 0.f;
    for (int w = 0; w <= Wn; ++w) {
      const int dt = Wn - w;
      if (t - dt < 0) continue;
      const short8* kp = (const short8*)(Km + base - (size_t)dt * H_DIM);
      short8 ka = kp[0], kb = kp[1];
      float d = 0.f;
      #pragma unroll
      for (int j = 0; j < 8; ++j) {
        d += q[j]     * bf2f((unsigned short)ka[j]);
        d += q[8 + j] * bf2f((unsigned short)kb[j]);
      }
      #pragma unroll
      for (int off = 32; off >= 1; off >>= 1) d += __shfl_xor(d, off, 64);
      const float s = d * scale;
      const float mn = fmaxf(m, s);
      const float corr = (m == -INFINITY) ? 0.f : __expf(m - mn);
      const float p = __expf(s - mn);
      l = l * corr + p;
      const short8* vp = (const short8*)(V + base - (size_t)dt * H_DIM);
      short8 va = vp[0], vb = vp[1];
      #pragma unroll
      for (int j = 0; j < 8; ++j) {
        o[j]     = o[j]     * corr + p * bf2f((unsigned short)va[j]);
        o[8 + j] = o[8 + j] * corr + p * bf2f((unsigned short)vb[j]);
      }
      m = mn;
    }
    const float inv = 1.f / l;
    float4* op = (float4*)(Out + base);
    op[0] = (float4){o[0]  * inv, o[1]  * inv, o[2]  * inv, o[3]  * inv};
    op[1] = (float4){o[4]  * inv, o[5]  * inv, o[6]  * inv, o[7]  * inv};
    op[2] = (float4){o[8]  * inv, o[9]  * inv, o[10] * inv, o[11] * inv};
    op[3] = (float4){o[12] * inv, o[13] * inv, o[14] * inv, o[15] * inv};
  }
}

extern "C" void kernel_launch(void* const* d_in, const int* in_sizes, int n_in,
                              void* d_out, int out_size, void* d_ws, size_t ws_size,
                              hipStream_t stream) {
  const float* X  = (const float*)d_in[0];
  const float* Wq = (const float*)d_in[1];
  const float* bq = (const float*)d_in[2];
  const float* Wk = (const float*)d_in[3];
  const float* bk = (const float*)d_in[4];
  const float* Wv = (const float*)d_in[5];
  const float* bv = (const float*)d_in[6];
  const int* winp = (const int*)d_in[7];

  const int M = in_sizes[0] / H_DIM;  // B*T = 16384
  const size_t MH = (size_t)M * H_DIM;
  const size_t HH = (size_t)H_DIM * H_DIM;

  // Workspace (bf16): Xb | Wqb | Wkb | Wvb | Qb | Kb | Vb  (~134 MiB)
  __hip_bfloat16* Xb  = (__hip_bfloat16*)d_ws;
  __hip_bfloat16* Wqb = Xb  + MH;
  __hip_bfloat16* Wkb = Wqb + HH;
  __hip_bfloat16* Wvb = Wkb + HH;
  __hip_bfloat16* Qb  = Wvb + HH;
  __hip_bfloat16* Kb  = Qb  + MH;
  __hip_bfloat16* Vb  = Kb  + MH;
  float* Out = (float*)d_out;

  // 1) f32 -> bf16 conversions.
  cvt_kernel<<<2048, 256, 0, stream>>>(X, Xb, (int)(MH / 8));
  cvt3_kernel<<<dim3(512, 3), 256, 0, stream>>>(Wq, Wk, Wv, Wqb, Wkb, Wvb,
                                                (int)(HH / 8));

  // 2) Fused QKV GEMM.
  dim3 g1(M / BM, 3 * (H_DIM / BN));  // 128 x 24
  qkv_gemm_kernel<<<g1, 256, 0, stream>>>(Xb, Wqb, Wkb, Wvb, bq, bk, bv,
                                          Qb, Kb, Vb, M);

  // 3) Windowed attention (f32 out).
  const int blocks = M / 4;  // 1 wave per row, 4 waves per block
  local_attn_kernel<<<blocks, 256, 0, stream>>>(Qb, Kb, Vb, winp, Out, M);
}